// Round 1
// baseline (149.259 us; speedup 1.0000x reference)
//
#include <hip/hip_runtime.h>

// Problem constants (fixed by reference)
#define BB 64
#define TT 512
#define MM 8
#define VMM 50
#define EPSV 1e-5f
#define WG 10   // w-group size (accumulators per group)
#define NG 5    // number of w-groups (NG*WG == VMM)

__device__ __forceinline__ float fast_rcp(float x) {
    return __builtin_amdgcn_rcpf(x);
}

// tanh(x) = 1 - 2/(exp(2x)+1); robust at +/-inf with fast exp/rcp
__device__ __forceinline__ float fast_tanh(float x) {
    float e2 = __expf(2.0f * x);
    return fmaf(-2.0f, fast_rcp(e2 + 1.0f), 1.0f);
}

__global__ __launch_bounds__(256, 4)
void intra_module_agg_kernel(const float* __restrict__ x,
                             const float* __restrict__ PA,
                             const float* __restrict__ conv_w,
                             const float* __restrict__ conv_b,
                             const float* __restrict__ bn_gamma,
                             const float* __restrict__ bn_beta,
                             const float* __restrict__ bn_mean,
                             const float* __restrict__ bn_var,
                             const float* __restrict__ w1,
                             const float* __restrict__ b1,
                             const float* __restrict__ w2,
                             const float* __restrict__ b2,
                             float* __restrict__ out)
{
    // grid = B*M*(T/256) = 64*8*2 = 1024 blocks of 256 threads
    const int blk = blockIdx.x;
    const int tt  = blk & 1;          // which half of T
    const int m   = (blk >> 1) & 7;   // module
    const int b   = blk >> 4;         // batch
    const int t   = tt * 256 + threadIdx.x;

    // ---- per-module constants (wave-uniform addresses -> scalar loads) ----
    const float scale = bn_gamma[m] * __frsqrt_rn(bn_var[m] + EPSV);
    const float Amul  = conv_w[m] * scale;                                // h = relu(agg*Amul + Cadd)
    const float Cadd  = (conv_b[m] - bn_mean[m]) * scale + bn_beta[m];
    float W1[8], B1[8], W2[8];
#pragma unroll
    for (int j = 0; j < 8; ++j) {
        W1[j] = w1[m * 8 + j];
        B1[j] = b1[m * 8 + j];
        W2[j] = w2[m * 8 + j];
    }
    const float B2 = b2[m];

    // ---- load this thread's x column: x[b, m*VM + v, t], stride T, coalesced ----
    const float* xb = x + ((b * (MM * VMM) + m * VMM) * TT + t);
    float xv[VMM];
#pragma unroll
    for (int v = 0; v < VMM; ++v) xv[v] = xb[v * TT];

    const float* pa = PA + m * (VMM * VMM);   // PA[m][v][w], row stride VM

    // ---- fused matvec + conv/BN/ReLU + attention MLP + online softmax ----
    // scores are bounded (|score| <= sum|w2| + |b2| since |tanh|<=1), so
    // softmax without max-subtraction is safe in fp32.
    float se = 0.0f;   // sum of exp(score)
    float sh = 0.0f;   // sum of h * exp(score)

#pragma unroll 1
    for (int g = 0; g < NG; ++g) {
        const float* pag = pa + g * WG;   // uniform pointer: columns [g*WG, g*WG+WG)

        float agg[WG];
#pragma unroll
        for (int w = 0; w < WG; ++w) agg[w] = 0.0f;

#pragma unroll
        for (int v = 0; v < VMM; ++v) {
#pragma unroll
            for (int w = 0; w < WG; ++w) {
                agg[w] = fmaf(xv[v], pag[v * VMM + w], agg[w]);
            }
        }

#pragma unroll
        for (int w = 0; w < WG; ++w) {
            float h = fmaf(agg[w], Amul, Cadd);
            h = fmaxf(h, 0.0f);
            float s = B2;
#pragma unroll
            for (int j = 0; j < 8; ++j) {
                float hid = fast_tanh(fmaf(h, W1[j], B1[j]));
                s = fmaf(hid, W2[j], s);
            }
            float e = __expf(s);
            se += e;
            sh = fmaf(h, e, sh);
        }
    }

    // out[b, m, t] for output shape [B, M, T, 1]
    out[(b * MM + m) * TT + t] = sh * fast_rcp(se);
}

extern "C" void kernel_launch(void* const* d_in, const int* in_sizes, int n_in,
                              void* d_out, int out_size, void* d_ws, size_t ws_size,
                              hipStream_t stream) {
    const float* x        = (const float*)d_in[0];
    const float* PA       = (const float*)d_in[1];
    const float* conv_w   = (const float*)d_in[2];
    const float* conv_b   = (const float*)d_in[3];
    const float* bn_gamma = (const float*)d_in[4];
    const float* bn_beta  = (const float*)d_in[5];
    const float* bn_mean  = (const float*)d_in[6];
    const float* bn_var   = (const float*)d_in[7];
    const float* w1       = (const float*)d_in[8];
    const float* b1       = (const float*)d_in[9];
    const float* w2       = (const float*)d_in[10];
    const float* b2       = (const float*)d_in[11];
    float* out = (float*)d_out;

    dim3 grid(BB * MM * (TT / 256));  // 1024
    dim3 block(256);
    intra_module_agg_kernel<<<grid, block, 0, stream>>>(
        x, PA, conv_w, conv_b, bn_gamma, bn_beta, bn_mean, bn_var,
        w1, b1, w2, b2, out);
}

// Round 2
// 145.570 us; speedup vs baseline: 1.0253x; 1.0253x over previous
//
#include <hip/hip_runtime.h>

// Problem constants (fixed by reference)
#define BB 64
#define TT 512
#define MM 8
#define VMM 50
#define EPSV 1e-5f

// exp(score(h)) lookup table
#define TN   1024
#define HMAX 16.0f
#define HSTEP (HMAX / TN)
#define INVH  (TN / HMAX)

__device__ __forceinline__ float fast_rcp(float x) {
    return __builtin_amdgcn_rcpf(x);
}

// tanh(x) = 1 - 2/(exp(2x)+1); robust at +/-inf. Only used in table build.
__device__ __forceinline__ float fast_tanh(float x) {
    float e2 = __expf(2.0f * x);
    return fmaf(-2.0f, fast_rcp(e2 + 1.0f), 1.0f);
}

__global__ __launch_bounds__(256, 4)
void intra_module_agg_kernel(const float* __restrict__ x,
                             const float* __restrict__ PA,
                             const float* __restrict__ conv_w,
                             const float* __restrict__ conv_b,
                             const float* __restrict__ bn_gamma,
                             const float* __restrict__ bn_beta,
                             const float* __restrict__ bn_mean,
                             const float* __restrict__ bn_var,
                             const float* __restrict__ w1,
                             const float* __restrict__ b1,
                             const float* __restrict__ w2,
                             const float* __restrict__ b2,
                             float* __restrict__ out)
{
    // grid = B*M*(T/256) = 1024 blocks of 256 threads; thread = one (b,m,t)
    const int blk = blockIdx.x;
    const int tt  = blk & 1;          // which half of T
    const int m   = (blk >> 1) & 7;   // module
    const int b   = blk >> 4;         // batch
    const int t   = tt * 256 + threadIdx.x;

    // ---- per-module affine constants (wave-uniform -> scalar regs) ----
    const float scale = bn_gamma[m] * __frsqrt_rn(bn_var[m] + EPSV);
    const float Amul  = conv_w[m] * scale;           // h = relu(agg*Amul + Cadd)
    const float Cadd  = (conv_b[m] - bn_mean[m]) * scale + bn_beta[m];

    // ---- build LDS table: g(h) = exp(score(h)), h in [0, HMAX] ----
    // score(h) = b2 + sum_j w2_j * tanh(h*w1_j + b1_j)  -- a fixed 1-D
    // function per module; |score| bounded by sum|w2|+|b2| so exp is safe.
    __shared__ float  graw[TN + 1];
    __shared__ float2 gtab[TN];
    {
        const float B2 = b2[m];
        for (int i = threadIdx.x; i < TN + 1; i += 256) {
            float h = i * HSTEP;
            float s = B2;
#pragma unroll
            for (int j = 0; j < 8; ++j) {
                s = fmaf(w2[m * 8 + j],
                         fast_tanh(fmaf(h, w1[m * 8 + j], b1[m * 8 + j])), s);
            }
            graw[i] = __expf(s);
        }
    }
    __syncthreads();
    for (int i = threadIdx.x; i < TN; i += 256) {
        gtab[i] = make_float2(graw[i], graw[i + 1] - graw[i]);
    }
    __syncthreads();

    // ---- matvec: acc[w] = sum_v x[v] * PA[m][v][w], all 50 acc live ----
    // x loads: stride T, coalesced across lanes, loaded exactly once.
    // PA addresses are wave-uniform with compile-time offsets -> s_load.
    const float* xb = x + ((b * (MM * VMM) + m * VMM) * TT + t);
    const float* pa = PA + m * (VMM * VMM);

    float acc[VMM];
#pragma unroll
    for (int w = 0; w < VMM; ++w) acc[w] = 0.0f;

#pragma unroll
    for (int v = 0; v < VMM; ++v) {
        const float xv = xb[v * TT];
#pragma unroll
        for (int w = 0; w < VMM; ++w) {
            acc[w] = fmaf(xv, pa[v * VMM + w], acc[w]);
        }
    }

    // ---- epilogue: h -> table lookup of exp(score), online softmax ----
    float se = 0.0f;   // sum of exp(score)
    float sh = 0.0f;   // sum of h * exp(score)
#pragma unroll
    for (int w = 0; w < VMM; ++w) {
        float h = fmaxf(fmaf(acc[w], Amul, Cadd), 0.0f);
        float u = fminf(h, HMAX - 0.0005f) * INVH;
        int   i = (int)u;
        float fr = u - (float)i;
        float2 p = gtab[i];
        float e = fmaf(fr, p.y, p.x);
        se += e;
        sh = fmaf(h, e, sh);
    }

    // out[b, m, t] for output shape [B, M, T, 1]
    out[(b * MM + m) * TT + t] = sh * fast_rcp(se);
}

extern "C" void kernel_launch(void* const* d_in, const int* in_sizes, int n_in,
                              void* d_out, int out_size, void* d_ws, size_t ws_size,
                              hipStream_t stream) {
    const float* x        = (const float*)d_in[0];
    const float* PA       = (const float*)d_in[1];
    const float* conv_w   = (const float*)d_in[2];
    const float* conv_b   = (const float*)d_in[3];
    const float* bn_gamma = (const float*)d_in[4];
    const float* bn_beta  = (const float*)d_in[5];
    const float* bn_mean  = (const float*)d_in[6];
    const float* bn_var   = (const float*)d_in[7];
    const float* w1       = (const float*)d_in[8];
    const float* b1       = (const float*)d_in[9];
    const float* w2       = (const float*)d_in[10];
    const float* b2       = (const float*)d_in[11];
    float* out = (float*)d_out;

    dim3 grid(BB * MM * (TT / 256));  // 1024
    dim3 block(256);
    intra_module_agg_kernel<<<grid, block, 0, stream>>>(
        x, PA, conv_w, conv_b, bn_gamma, bn_beta, bn_mean, bn_var,
        w1, b1, w2, b2, out);
}

// Round 3
// 125.098 us; speedup vs baseline: 1.1931x; 1.1636x over previous
//
#include <hip/hip_runtime.h>

// Problem constants (fixed by reference)
#define BB 64
#define TT 512
#define MM 8
#define VMM 50
#define VPAD 52          // LDS row pad: 52 floats = 208 B (16B-aligned rows)
#define EPSV 1e-5f

// exp(score(h)) lookup table
#define TN   1024
#define HMAX 16.0f
#define HSTEP (HMAX / TN)
#define INVH  (TN / HMAX)

__device__ __forceinline__ float fast_rcp(float x) {
    return __builtin_amdgcn_rcpf(x);
}

// tanh(x) = 1 - 2/(exp(2x)+1); robust at +/-inf. Only used in table build.
__device__ __forceinline__ float fast_tanh(float x) {
    float e2 = __expf(2.0f * x);
    return fmaf(-2.0f, fast_rcp(e2 + 1.0f), 1.0f);
}

__global__ __launch_bounds__(256, 4)
void intra_module_agg_kernel(const float* __restrict__ x,
                             const float* __restrict__ PA,
                             const float* __restrict__ conv_w,
                             const float* __restrict__ conv_b,
                             const float* __restrict__ bn_gamma,
                             const float* __restrict__ bn_beta,
                             const float* __restrict__ bn_mean,
                             const float* __restrict__ bn_var,
                             const float* __restrict__ w1,
                             const float* __restrict__ b1,
                             const float* __restrict__ w2,
                             const float* __restrict__ b2,
                             float* __restrict__ out)
{
    // grid = B*M*(T/256) = 1024 blocks of 256 threads; thread = one (b,m,t)
    const int blk = blockIdx.x;
    const int tt  = blk & 1;          // which half of T
    const int m   = (blk >> 1) & 7;   // module
    const int b   = blk >> 4;         // batch
    const int t   = tt * 256 + threadIdx.x;

    __shared__ float  paL[VMM * VPAD];   // 10.4 KB: PA[m] padded rows
    __shared__ float  graw[TN + 1];      //  4.1 KB
    __shared__ float2 gtab[TN];          //  8.2 KB

    // ---- per-module affine constants (wave-uniform -> scalar regs) ----
    const float scale = bn_gamma[m] * __frsqrt_rn(bn_var[m] + EPSV);
    const float Amul  = conv_w[m] * scale;           // h = relu(agg*Amul + Cadd)
    const float Cadd  = (conv_b[m] - bn_mean[m]) * scale + bn_beta[m];

    // ---- stage PA[m] into LDS (padded rows) ----
    {
        const float* pa = PA + m * (VMM * VMM);
        for (int idx = threadIdx.x; idx < VMM * VMM; idx += 256) {
            int r = idx / VMM;
            int c = idx - r * VMM;
            paL[r * VPAD + c] = pa[idx];
        }
    }

    // ---- build LDS table: g(h) = exp(score(h)), h in [0, HMAX] ----
    {
        const float B2 = b2[m];
        for (int i = threadIdx.x; i < TN + 1; i += 256) {
            float h = i * HSTEP;
            float s = B2;
#pragma unroll
            for (int j = 0; j < 8; ++j) {
                s = fmaf(w2[m * 8 + j],
                         fast_tanh(fmaf(h, w1[m * 8 + j], b1[m * 8 + j])), s);
            }
            graw[i] = __expf(s);
        }
    }
    __syncthreads();
    for (int i = threadIdx.x; i < TN; i += 256) {
        gtab[i] = make_float2(graw[i], graw[i + 1] - graw[i]);
    }
    __syncthreads();

    // ---- matvec: acc[w] = sum_v x[v] * PA[m][v][w] ----
    // x: stride-T loads, coalesced across lanes, pinned into VGPRs so the
    // compiler cannot sink/reload them. PA: uniform-address ds_read_b128
    // broadcast (conflict-free), 4 FMAs per read -> LDS pipe hides under VALU.
    const float* xb = x + ((b * (MM * VMM) + m * VMM) * TT + t);

    float acc[VMM];
#pragma unroll
    for (int w = 0; w < VMM; ++w) acc[w] = 0.0f;

#pragma unroll 1
    for (int half = 0; half < 2; ++half) {
        float xv[25];
#pragma unroll
        for (int v = 0; v < 25; ++v) xv[v] = xb[(half * 25 + v) * TT];
#pragma unroll
        for (int v = 0; v < 25; ++v) asm volatile("" : "+v"(xv[v]));

#pragma unroll
        for (int v = 0; v < 25; ++v) {
            const float4* row = (const float4*)&paL[(half * 25 + v) * VPAD];
#pragma unroll
            for (int c = 0; c < 13; ++c) {
                float4 p = row[c];
                if (4 * c + 0 < VMM) acc[4 * c + 0] = fmaf(xv[v], p.x, acc[4 * c + 0]);
                if (4 * c + 1 < VMM) acc[4 * c + 1] = fmaf(xv[v], p.y, acc[4 * c + 1]);
                if (4 * c + 2 < VMM) acc[4 * c + 2] = fmaf(xv[v], p.z, acc[4 * c + 2]);
                if (4 * c + 3 < VMM) acc[4 * c + 3] = fmaf(xv[v], p.w, acc[4 * c + 3]);
            }
        }
    }

    // ---- epilogue: h -> table lookup of exp(score), online softmax ----
    float se = 0.0f;   // sum of exp(score)
    float sh = 0.0f;   // sum of h * exp(score)
#pragma unroll
    for (int w = 0; w < VMM; ++w) {
        float h = fmaxf(fmaf(acc[w], Amul, Cadd), 0.0f);
        float u = fminf(h, HMAX - 0.0005f) * INVH;
        int   i = (int)u;
        float fr = u - (float)i;
        float2 p = gtab[i];
        float e = fmaf(fr, p.y, p.x);
        se += e;
        sh = fmaf(h, e, sh);
    }

    // out[b, m, t] for output shape [B, M, T, 1]
    out[(b * MM + m) * TT + t] = sh * fast_rcp(se);
}

extern "C" void kernel_launch(void* const* d_in, const int* in_sizes, int n_in,
                              void* d_out, int out_size, void* d_ws, size_t ws_size,
                              hipStream_t stream) {
    const float* x        = (const float*)d_in[0];
    const float* PA       = (const float*)d_in[1];
    const float* conv_w   = (const float*)d_in[2];
    const float* conv_b   = (const float*)d_in[3];
    const float* bn_gamma = (const float*)d_in[4];
    const float* bn_beta  = (const float*)d_in[5];
    const float* bn_mean  = (const float*)d_in[6];
    const float* bn_var   = (const float*)d_in[7];
    const float* w1       = (const float*)d_in[8];
    const float* b1       = (const float*)d_in[9];
    const float* w2       = (const float*)d_in[10];
    const float* b2       = (const float*)d_in[11];
    float* out = (float*)d_out;

    dim3 grid(BB * MM * (TT / 256));  // 1024
    dim3 block(256);
    intra_module_agg_kernel<<<grid, block, 0, stream>>>(
        x, PA, conv_w, conv_b, bn_gamma, bn_beta, bn_mean, bn_var,
        w1, b1, w2, b2, out);
}

// Round 4
// 116.258 us; speedup vs baseline: 1.2839x; 1.0760x over previous
//
#include <hip/hip_runtime.h>

// Problem constants (fixed by reference)
#define BB 64
#define TT 512
#define MM 8
#define VMM 50
#define KP 64            // K (=v) padded
#define NP 64            // N (=w) padded
#define RSTRIDE 36       // u32 per LDS row: 32 u32 data (64 bf16) + 4 pad
#define EPSV 1e-5f

// exp(score(h)) lookup table
#define TN   1024
#define HMAX 16.0f
#define HSTEP (HMAX / TN)
#define INVH  (TN / HMAX)

using short8  = __attribute__((ext_vector_type(8))) short;
using float4v = __attribute__((ext_vector_type(4))) float;

__device__ __forceinline__ float fast_rcp(float x) {
    return __builtin_amdgcn_rcpf(x);
}
__device__ __forceinline__ float fast_tanh(float x) {
    float e2 = __expf(2.0f * x);
    return fmaf(-2.0f, fast_rcp(e2 + 1.0f), 1.0f);
}
// round-to-nearest-even f32 -> bf16, packed pair into u32
__device__ __forceinline__ unsigned f2bf(float f) {
    unsigned u = __float_as_uint(f);
    return (u + 0x7FFFu + ((u >> 16) & 1u)) >> 16;
}
__device__ __forceinline__ unsigned pack2(float lo, float hi) {
    return f2bf(lo) | (f2bf(hi) << 16);
}

__global__ __launch_bounds__(256, 2)
void intra_module_agg_kernel(const float* __restrict__ x,
                             const float* __restrict__ PA,
                             const float* __restrict__ conv_w,
                             const float* __restrict__ conv_b,
                             const float* __restrict__ bn_gamma,
                             const float* __restrict__ bn_beta,
                             const float* __restrict__ bn_mean,
                             const float* __restrict__ bn_var,
                             const float* __restrict__ w1,
                             const float* __restrict__ b1,
                             const float* __restrict__ w2,
                             const float* __restrict__ b2,
                             float* __restrict__ out)
{
    // grid = B*M*(T/256) = 1024 blocks of 256 threads (4 waves)
    const int blk = blockIdx.x;
    const int tt  = blk & 1;
    const int m   = (blk >> 1) & 7;
    const int b   = blk >> 4;
    const int j   = threadIdx.x;

    __shared__ __align__(16) unsigned xsu[256 * RSTRIDE]; // X tile bf16 [t][v]
    __shared__ __align__(16) unsigned psu[NP * RSTRIDE];  // PA^T bf16 [w][v]
    __shared__ float  graw[TN + 1];
    __shared__ float2 gtab[TN];

    // ---- per-module affine constants ----
    const float scale = bn_gamma[m] * __frsqrt_rn(bn_var[m] + EPSV);
    const float Amul  = conv_w[m] * scale;
    const float Cadd  = (conv_b[m] - bn_mean[m]) * scale + bn_beta[m];

    // ---- stage X tile: thread j = local t; v pairs packed to bf16x2 ----
    {
        const float* xb = x + ((b * (MM * VMM) + m * VMM) * TT + tt * 256 + j);
#pragma unroll
        for (int vp = 0; vp < 25; ++vp) {
            float a = xb[(2 * vp) * TT];
            float c = xb[(2 * vp + 1) * TT];
            xsu[j * RSTRIDE + vp] = pack2(a, c);
        }
#pragma unroll
        for (int vp = 25; vp < 32; ++vp) xsu[j * RSTRIDE + vp] = 0u;  // K pad
    }

    // ---- stage PA^T (w rows, v cols), zero-padded to 64x64 ----
    {
        const float* pa = PA + m * (VMM * VMM);
        const int w  = j & 63;
        const int vb = (j >> 6) * 8;
#pragma unroll
        for (int i = 0; i < 8; ++i) {
            int vp = vb + i, v0 = 2 * vp, v1 = v0 + 1;
            float a = (w < VMM && v0 < VMM) ? pa[v0 * VMM + w] : 0.0f;
            float c = (w < VMM && v1 < VMM) ? pa[v1 * VMM + w] : 0.0f;
            psu[w * RSTRIDE + vp] = pack2(a, c);
        }
    }

    // ---- graw: g(h) = exp(score(h)) samples ----
    {
        const float B2 = b2[m];
        for (int i = j; i < TN + 1; i += 256) {
            float h = i * HSTEP;
            float s = B2;
#pragma unroll
            for (int k = 0; k < 8; ++k)
                s = fmaf(w2[m * 8 + k],
                         fast_tanh(fmaf(h, w1[m * 8 + k], b1[m * 8 + k])), s);
            graw[i] = __expf(s);
        }
    }
    __syncthreads();

    // gtab (value, delta) — runs before this thread's MFMA; barrier 2 covers it
    for (int i = j; i < TN; i += 256)
        gtab[i] = make_float2(graw[i], graw[i + 1] - graw[i]);

    // ---- MFMA: C[t, w] = sum_v X[t,v] * PA[v,w] ----
    const int lane = j & 63, wv = j >> 6;
    const int q = lane >> 4, nl = lane & 15;

    short8 Bf[4][2];
#pragma unroll
    for (int nt = 0; nt < 4; ++nt)
#pragma unroll
        for (int ks = 0; ks < 2; ++ks)
            Bf[nt][ks] = *(const short8*)&psu[(nt * 16 + nl) * RSTRIDE + ks * 16 + q * 4];

    float4v C[4][4];
#pragma unroll
    for (int mt = 0; mt < 4; ++mt)
#pragma unroll
        for (int nt = 0; nt < 4; ++nt)
            C[mt][nt] = (float4v){0.f, 0.f, 0.f, 0.f};

#pragma unroll
    for (int mt = 0; mt < 4; ++mt) {
        const int row = (wv * 4 + mt) * 16 + nl;   // A row m = lane&15
        short8 A0 = *(const short8*)&xsu[row * RSTRIDE + 0 * 16 + q * 4];
        short8 A1 = *(const short8*)&xsu[row * RSTRIDE + 1 * 16 + q * 4];
#pragma unroll
        for (int nt = 0; nt < 4; ++nt) {
            C[mt][nt] = __builtin_amdgcn_mfma_f32_16x16x32_bf16(A0, Bf[nt][0], C[mt][nt], 0, 0, 0);
            C[mt][nt] = __builtin_amdgcn_mfma_f32_16x16x32_bf16(A1, Bf[nt][1], C[mt][nt], 0, 0, 0);
        }
    }
    __syncthreads();   // gtab complete before lookups

    // ---- epilogue: h -> table exp(score), softmax over w via shfl_xor ----
    const int obase = (b * MM + m) * TT + tt * 256;
#pragma unroll
    for (int mt = 0; mt < 4; ++mt) {
        float se[4] = {0.f, 0.f, 0.f, 0.f};
        float sh[4] = {0.f, 0.f, 0.f, 0.f};
#pragma unroll
        for (int nt = 0; nt < 4; ++nt) {
            const bool ok = (nt * 16 + nl) < VMM;   // mask padded w columns
#pragma unroll
            for (int r = 0; r < 4; ++r) {
                float h = fmaxf(fmaf(C[mt][nt][r], Amul, Cadd), 0.0f);
                float u = fminf(h, HMAX - 0.0005f) * INVH;
                int   i = (int)u;
                float fr = u - (float)i;
                float2 p = gtab[i];
                float e = ok ? fmaf(fr, p.y, p.x) : 0.0f;
                se[r] += e;
                sh[r] = fmaf(h, e, sh[r]);
            }
        }
#pragma unroll
        for (int r = 0; r < 4; ++r) {
#pragma unroll
            for (int mk = 1; mk < 16; mk <<= 1) {
                se[r] += __shfl_xor(se[r], mk, 64);
                sh[r] += __shfl_xor(sh[r], mk, 64);
            }
        }
        if (nl == 0) {
#pragma unroll
            for (int r = 0; r < 4; ++r)
                out[obase + (wv * 4 + mt) * 16 + q * 4 + r] = sh[r] * fast_rcp(se[r]);
        }
    }
}

extern "C" void kernel_launch(void* const* d_in, const int* in_sizes, int n_in,
                              void* d_out, int out_size, void* d_ws, size_t ws_size,
                              hipStream_t stream) {
    const float* x        = (const float*)d_in[0];
    const float* PA       = (const float*)d_in[1];
    const float* conv_w   = (const float*)d_in[2];
    const float* conv_b   = (const float*)d_in[3];
    const float* bn_gamma = (const float*)d_in[4];
    const float* bn_beta  = (const float*)d_in[5];
    const float* bn_mean  = (const float*)d_in[6];
    const float* bn_var   = (const float*)d_in[7];
    const float* w1       = (const float*)d_in[8];
    const float* b1       = (const float*)d_in[9];
    const float* w2       = (const float*)d_in[10];
    const float* b2       = (const float*)d_in[11];
    float* out = (float*)d_out;

    dim3 grid(BB * MM * (TT / 256));  // 1024
    dim3 block(256);
    intra_module_agg_kernel<<<grid, block, 0, stream>>>(
        x, PA, conv_w, conv_b, bn_gamma, bn_beta, bn_mean, bn_var,
        w1, b1, w2, b2, out);
}

// Round 6
// 113.639 us; speedup vs baseline: 1.3134x; 1.0230x over previous
//
#include <hip/hip_runtime.h>

// Problem constants (fixed by reference)
#define BB 64
#define TT 512
#define MM 8
#define VMM 50
#define TBLK 128         // t per block
#define RSTRIDE 36       // u32 per LDS row: 32 data (64 bf16) + 4 pad
#define EPSV 1e-5f

// exp(score(h)-s0) lookup table, fp16x2-packed (value, delta)
#define TN   1024
#define HMAX 16.0f
#define HSTEP (HMAX / TN)
#define INVH  (TN / HMAX)

using short8  = __attribute__((ext_vector_type(8))) short;
using float4v = __attribute__((ext_vector_type(4))) float;

__device__ __forceinline__ float fast_rcp(float x) {
    return __builtin_amdgcn_rcpf(x);
}
__device__ __forceinline__ float fast_tanh(float x) {
    float e2 = __expf(2.0f * x);
    return fmaf(-2.0f, fast_rcp(e2 + 1.0f), 1.0f);
}
// round-to-nearest-even f32 -> bf16 pair packed into u32
__device__ __forceinline__ unsigned f2bf(float f) {
    unsigned u = __float_as_uint(f);
    return (u + 0x7FFFu + ((u >> 16) & 1u)) >> 16;
}
__device__ __forceinline__ unsigned pack2(float lo, float hi) {
    return f2bf(lo) | (f2bf(hi) << 16);
}
// f32 pair -> fp16x2 packed u32 (compiler-native _Float16, no fp16 header)
__device__ __forceinline__ unsigned packh2(float lo, float hi) {
    unsigned short a = __builtin_bit_cast(unsigned short, (_Float16)lo);
    unsigned short b = __builtin_bit_cast(unsigned short, (_Float16)hi);
    return (unsigned)a | ((unsigned)b << 16);
}
__device__ __forceinline__ float h2f_lo(unsigned p) {
    return (float)__builtin_bit_cast(_Float16, (unsigned short)(p & 0xFFFFu));
}
__device__ __forceinline__ float h2f_hi(unsigned p) {
    return (float)__builtin_bit_cast(_Float16, (unsigned short)(p >> 16));
}

__global__ __launch_bounds__(256, 4)
void intra_module_agg_kernel(const float* __restrict__ x,
                             const float* __restrict__ PA,
                             const float* __restrict__ conv_w,
                             const float* __restrict__ conv_b,
                             const float* __restrict__ bn_gamma,
                             const float* __restrict__ bn_beta,
                             const float* __restrict__ bn_mean,
                             const float* __restrict__ bn_var,
                             const float* __restrict__ w1,
                             const float* __restrict__ b1,
                             const float* __restrict__ w2,
                             const float* __restrict__ b2,
                             float* __restrict__ out)
{
    // grid = B*M*(T/128) = 2048 blocks of 256 threads (4 waves)
    const int blk = blockIdx.x;
    const int tq  = blk & 3;          // T quarter
    const int m   = (blk >> 2) & 7;   // module
    const int b   = blk >> 5;         // batch
    const int j   = threadIdx.x;

    __shared__ __align__(16) unsigned xsu[TBLK * RSTRIDE]; // 18.4 KB X bf16 [t][v]
    __shared__ __align__(16) unsigned psu[64 * RSTRIDE];   //  9.2 KB PA^T bf16 [w][v]
    __shared__ unsigned gt[TN];                            //  4.1 KB fp16x2 table

    // ---- per-module affine constants (wave-uniform -> scalar regs) ----
    const float scale = bn_gamma[m] * __frsqrt_rn(bn_var[m] + EPSV);
    const float Amul  = conv_w[m] * scale;
    const float Cadd  = (conv_b[m] - bn_mean[m]) * scale + bn_beta[m];

    // ---- stage X: 2 threads per t-row, bf16x2-packed, K zero-padded ----
    {
        const int t  = j >> 1;        // 0..127 local t
        const int hf = j & 1;         // which v-half this thread covers
        const float* xb = x + ((b * (MM * VMM) + m * VMM) * TT + tq * TBLK + t);
        unsigned* row = &xsu[t * RSTRIDE];
        const int vp0 = hf * 13;
#pragma unroll
        for (int i = 0; i < 13; ++i) {
            int vp = vp0 + i;
            float a = 0.0f, c = 0.0f;
            if (vp < 25) { a = xb[(2 * vp) * TT]; c = xb[(2 * vp + 1) * TT]; }
            row[vp] = pack2(a, c);
        }
        if (hf) {
#pragma unroll
            for (int vp = 26; vp < 32; ++vp) row[vp] = 0u;
        }
    }

    // ---- stage PA^T (w rows, v cols), zero-padded to 64x64 ----
    {
        const float* pa = PA + m * (VMM * VMM);
        const int w  = j & 63;
        const int vb = (j >> 6) * 8;
#pragma unroll
        for (int i = 0; i < 8; ++i) {
            int vp = vb + i, v0 = 2 * vp, v1 = v0 + 1;
            float a = (w < VMM && v0 < VMM) ? pa[v0 * VMM + w] : 0.0f;
            float c = (w < VMM && v1 < VMM) ? pa[v1 * VMM + w] : 0.0f;
            psu[w * RSTRIDE + vp] = pack2(a, c);
        }
    }

    // ---- build table: gt[i] = fp16x2(g_i, g_{i+1}-g_i), g = exp(score-s0) ----
    // softmax is invariant to the uniform shift s0; s0 = smax-8 keeps exp()
    // safely inside fp16 range (max ~e^8).
    {
        float W1[8], B1[8], W2[8];
        float B2 = b2[m], sabs = 0.0f;
#pragma unroll
        for (int k = 0; k < 8; ++k) {
            W1[k] = w1[m * 8 + k];
            B1[k] = b1[m * 8 + k];
            W2[k] = w2[m * 8 + k];
            sabs += fabsf(W2[k]);
        }
        const float s0 = (B2 + sabs) - 8.0f;   // wave-uniform, bit-identical
        float gv[5];
#pragma unroll
        for (int k = 0; k < 5; ++k) {
            float h = (4 * j + k) * HSTEP;
            float s = B2 - s0;
#pragma unroll
            for (int i = 0; i < 8; ++i)
                s = fmaf(W2[i], fast_tanh(fmaf(h, W1[i], B1[i])), s);
            gv[k] = __expf(s);
        }
#pragma unroll
        for (int k = 0; k < 4; ++k)
            gt[4 * j + k] = packh2(gv[k], gv[k + 1] - gv[k]);
    }

    __syncthreads();

    // ---- MFMA: C[w, t] = sum_v PA[v,w] * X[t,v]  (A from psu, B from xsu) ----
    const int lane = j & 63, wv = j >> 6;
    const int q = lane >> 4, nl = lane & 15;

    short8 A[4][2];
#pragma unroll
    for (int wt = 0; wt < 4; ++wt)
#pragma unroll
        for (int ks = 0; ks < 2; ++ks)
            A[wt][ks] = *(const short8*)&psu[(wt * 16 + nl) * RSTRIDE + ks * 16 + q * 4];

    float4v C[2][4];
#pragma unroll
    for (int t2 = 0; t2 < 2; ++t2)
#pragma unroll
        for (int wt = 0; wt < 4; ++wt)
            C[t2][wt] = (float4v){0.f, 0.f, 0.f, 0.f};

#pragma unroll
    for (int t2 = 0; t2 < 2; ++t2) {
        const int trow = (wv * 2 + t2) * 16 + nl;
        short8 Bv0 = *(const short8*)&xsu[trow * RSTRIDE + 0 * 16 + q * 4];
        short8 Bv1 = *(const short8*)&xsu[trow * RSTRIDE + 1 * 16 + q * 4];
#pragma unroll
        for (int wt = 0; wt < 4; ++wt) {
            C[t2][wt] = __builtin_amdgcn_mfma_f32_16x16x32_bf16(A[wt][0], Bv0, C[t2][wt], 0, 0, 0);
            C[t2][wt] = __builtin_amdgcn_mfma_f32_16x16x32_bf16(A[wt][1], Bv1, C[t2][wt], 0, 0, 0);
        }
    }

    // ---- epilogue: table softmax over w (rows in-thread, quads via shfl) ----
    const int obase = (b * MM + m) * TT + tq * TBLK;
#pragma unroll
    for (int t2 = 0; t2 < 2; ++t2) {
        float se = 0.0f, sh = 0.0f;
#pragma unroll
        for (int wt = 0; wt < 4; ++wt) {
#pragma unroll
            for (int r = 0; r < 4; ++r) {
                const int w = wt * 16 + q * 4 + r;
                float h = fmaxf(fmaf(C[t2][wt][r], Amul, Cadd), 0.0f);
                float u = fminf(h, HMAX - 0.0005f) * INVH;
                int   i = (int)u;
                float fr = u - (float)i;
                unsigned p = gt[i];
                float e = (w < VMM) ? fmaf(fr, h2f_hi(p), h2f_lo(p)) : 0.0f;
                se += e;
                sh = fmaf(h, e, sh);
            }
        }
        se += __shfl_xor(se, 16, 64);
        se += __shfl_xor(se, 32, 64);
        sh += __shfl_xor(sh, 16, 64);
        sh += __shfl_xor(sh, 32, 64);
        if (q == 0)
            out[obase + (wv * 2 + t2) * 16 + nl] = sh * fast_rcp(se);
    }
}

extern "C" void kernel_launch(void* const* d_in, const int* in_sizes, int n_in,
                              void* d_out, int out_size, void* d_ws, size_t ws_size,
                              hipStream_t stream) {
    const float* x        = (const float*)d_in[0];
    const float* PA       = (const float*)d_in[1];
    const float* conv_w   = (const float*)d_in[2];
    const float* conv_b   = (const float*)d_in[3];
    const float* bn_gamma = (const float*)d_in[4];
    const float* bn_beta  = (const float*)d_in[5];
    const float* bn_mean  = (const float*)d_in[6];
    const float* bn_var   = (const float*)d_in[7];
    const float* w1       = (const float*)d_in[8];
    const float* b1       = (const float*)d_in[9];
    const float* w2       = (const float*)d_in[10];
    const float* b2       = (const float*)d_in[11];
    float* out = (float*)d_out;

    dim3 grid(BB * MM * (TT / TBLK));  // 2048
    dim3 block(256);
    intra_module_agg_kernel<<<grid, block, 0, stream>>>(
        x, PA, conv_w, conv_b, bn_gamma, bn_beta, bn_mean, bn_var,
        w1, b1, w2, b2, out);
}

// Round 7
// 112.545 us; speedup vs baseline: 1.3262x; 1.0097x over previous
//
#include <hip/hip_runtime.h>

// Problem constants (fixed by reference)
#define BB 64
#define TT 512
#define MM 8
#define VMM 50
#define TBLK 128         // t per block (main kernel)
#define RSTRIDE 36       // u32 per LDS row: 32 data (64 bf16) + 4 pad
#define EPSV 1e-5f

// exp(score(h)-s0) lookup table, fp16x2-packed (value, delta)
#define TN   1024
#define HMAX 16.0f
#define HSTEP (HMAX / TN)
#define INVH  (TN / HMAX)

// d_ws layout (u32 units): [m*TN] 8 tables; then 8 x (64x32) packed PA^T
#define WS_GT(m)  ((m) * TN)
#define WS_PA(m)  (MM * TN + (m) * (64 * 32))
#define WS_NEED   ((MM * TN + MM * 64 * 32) * 4)   // 98304 bytes

using short8  = __attribute__((ext_vector_type(8))) short;
using float4v = __attribute__((ext_vector_type(4))) float;

__device__ __forceinline__ float fast_rcp(float x) {
    return __builtin_amdgcn_rcpf(x);
}
__device__ __forceinline__ float fast_tanh(float x) {
    float e2 = __expf(2.0f * x);
    return fmaf(-2.0f, fast_rcp(e2 + 1.0f), 1.0f);
}
// round-to-nearest-even f32 -> bf16 pair packed into u32
__device__ __forceinline__ unsigned f2bf(float f) {
    unsigned u = __float_as_uint(f);
    return (u + 0x7FFFu + ((u >> 16) & 1u)) >> 16;
}
__device__ __forceinline__ unsigned pack2(float lo, float hi) {
    return f2bf(lo) | (f2bf(hi) << 16);
}
// f32 pair -> fp16x2 packed u32 (compiler-native _Float16, no fp16 header)
__device__ __forceinline__ unsigned packh2(float lo, float hi) {
    unsigned short a = __builtin_bit_cast(unsigned short, (_Float16)lo);
    unsigned short b = __builtin_bit_cast(unsigned short, (_Float16)hi);
    return (unsigned)a | ((unsigned)b << 16);
}
__device__ __forceinline__ float h2f_lo(unsigned p) {
    return (float)__builtin_bit_cast(_Float16, (unsigned short)(p & 0xFFFFu));
}
__device__ __forceinline__ float h2f_hi(unsigned p) {
    return (float)__builtin_bit_cast(_Float16, (unsigned short)(p >> 16));
}

// ---------------- prep kernel: 8 blocks, one per module ----------------
// Builds per-module exp(score-s0) table (fp16x2) and bf16-packed PA^T
// into d_ws. Runs once per call; ~2-3 us.
__global__ __launch_bounds__(256, 4)
void prep_kernel(const float* __restrict__ PA,
                 const float* __restrict__ w1,
                 const float* __restrict__ b1,
                 const float* __restrict__ w2,
                 const float* __restrict__ b2,
                 unsigned* __restrict__ ws)
{
    const int m = blockIdx.x;
    const int j = threadIdx.x;

    // ---- table ----
    {
        float W1[8], B1[8], W2[8];
        float B2 = b2[m], sabs = 0.0f;
#pragma unroll
        for (int k = 0; k < 8; ++k) {
            W1[k] = w1[m * 8 + k];
            B1[k] = b1[m * 8 + k];
            W2[k] = w2[m * 8 + k];
            sabs += fabsf(W2[k]);
        }
        const float s0 = (B2 + sabs) - 8.0f;   // uniform shift; exp in fp16 range
        float gv[5];
#pragma unroll
        for (int k = 0; k < 5; ++k) {
            float h = (4 * j + k) * HSTEP;
            float s = B2 - s0;
#pragma unroll
            for (int i = 0; i < 8; ++i)
                s = fmaf(W2[i], fast_tanh(fmaf(h, W1[i], B1[i])), s);
            gv[k] = __expf(s);
        }
#pragma unroll
        for (int k = 0; k < 4; ++k)
            ws[WS_GT(m) + 4 * j + k] = packh2(gv[k], gv[k + 1] - gv[k]);
    }

    // ---- PA^T pack: rows w (0..63), cols vp (0..31), zero-padded ----
    {
        const float* pa = PA + m * (VMM * VMM);
        const int w  = j & 63;
        const int vb = (j >> 6) * 8;
#pragma unroll
        for (int i = 0; i < 8; ++i) {
            int vp = vb + i, v0 = 2 * vp, v1 = v0 + 1;
            float a = (w < VMM && v0 < VMM) ? pa[v0 * VMM + w] : 0.0f;
            float c = (w < VMM && v1 < VMM) ? pa[v1 * VMM + w] : 0.0f;
            ws[WS_PA(m) + w * 32 + vp] = pack2(a, c);
        }
    }
}

// ---------------- main kernel: grid = B*M*(T/128) = 2048 ----------------
__global__ __launch_bounds__(256, 4)
void intra_module_agg_kernel(const float* __restrict__ x,
                             const float* __restrict__ conv_w,
                             const float* __restrict__ conv_b,
                             const float* __restrict__ bn_gamma,
                             const float* __restrict__ bn_beta,
                             const float* __restrict__ bn_mean,
                             const float* __restrict__ bn_var,
                             const unsigned* __restrict__ ws,
                             float* __restrict__ out)
{
    const int blk = blockIdx.x;
    const int tq  = blk & 3;          // T quarter
    const int m   = (blk >> 2) & 7;   // module
    const int b   = blk >> 5;         // batch
    const int j   = threadIdx.x;

    __shared__ __align__(16) unsigned xsu[TBLK * RSTRIDE]; // 18.4 KB X bf16 [t][v]
    __shared__ __align__(16) unsigned psu[64 * RSTRIDE];   //  9.2 KB PA^T bf16 [w][v]
    __shared__ __align__(16) unsigned gt[TN];              //  4.1 KB fp16x2 table

    // ---- per-module affine constants (wave-uniform -> scalar regs) ----
    const float scale = bn_gamma[m] * __frsqrt_rn(bn_var[m] + EPSV);
    const float Amul  = conv_w[m] * scale;
    const float Cadd  = (conv_b[m] - bn_mean[m]) * scale + bn_beta[m];

    // ---- copy table from ws: 1024 u32, 1 dwordx4 + 1 b128 write/thread ----
    {
        uint4 g = ((const uint4*)(ws + WS_GT(m)))[j];
        *(uint4*)&gt[4 * j] = g;
    }
    // ---- copy PA^T from ws: 2048 u32 = 512 uint4, 2 per thread ----
    {
        const uint4* src = (const uint4*)(ws + WS_PA(m));
#pragma unroll
        for (int p = 0; p < 2; ++p) {
            int i4 = j + p * 256;
            uint4 v = src[i4];
            int r = i4 >> 3;            // 8 uint4 per 32-u32 row
            int c = (i4 & 7) * 4;
            *(uint4*)&psu[r * RSTRIDE + c] = v;
        }
    }

    // ---- stage X: 2 threads per t-row, bf16x2-packed, K zero-padded ----
    {
        const int t  = j >> 1;        // 0..127 local t
        const int hf = j & 1;         // which v-half this thread covers
        const float* xb = x + ((b * (MM * VMM) + m * VMM) * TT + tq * TBLK + t);
        unsigned* row = &xsu[t * RSTRIDE];
        const int vp0 = hf * 13;
#pragma unroll
        for (int i = 0; i < 13; ++i) {
            int vp = vp0 + i;
            float a = 0.0f, c = 0.0f;
            if (vp < 25) { a = xb[(2 * vp) * TT]; c = xb[(2 * vp + 1) * TT]; }
            row[vp] = pack2(a, c);
        }
        if (hf) {
#pragma unroll
            for (int vp = 26; vp < 32; ++vp) row[vp] = 0u;
        }
    }

    __syncthreads();

    // ---- MFMA: C[w, t] = sum_v PA[v,w] * X[t,v]  (A from psu, B from xsu) ----
    const int lane = j & 63, wv = j >> 6;
    const int q = lane >> 4, nl = lane & 15;

    short8 A[4][2];
#pragma unroll
    for (int wt = 0; wt < 4; ++wt)
#pragma unroll
        for (int ks = 0; ks < 2; ++ks)
            A[wt][ks] = *(const short8*)&psu[(wt * 16 + nl) * RSTRIDE + ks * 16 + q * 4];

    float4v C[2][4];
#pragma unroll
    for (int t2 = 0; t2 < 2; ++t2)
#pragma unroll
        for (int wt = 0; wt < 4; ++wt)
            C[t2][wt] = (float4v){0.f, 0.f, 0.f, 0.f};

#pragma unroll
    for (int t2 = 0; t2 < 2; ++t2) {
        const int trow = (wv * 2 + t2) * 16 + nl;
        short8 Bv0 = *(const short8*)&xsu[trow * RSTRIDE + 0 * 16 + q * 4];
        short8 Bv1 = *(const short8*)&xsu[trow * RSTRIDE + 1 * 16 + q * 4];
#pragma unroll
        for (int wt = 0; wt < 4; ++wt) {
            C[t2][wt] = __builtin_amdgcn_mfma_f32_16x16x32_bf16(A[wt][0], Bv0, C[t2][wt], 0, 0, 0);
            C[t2][wt] = __builtin_amdgcn_mfma_f32_16x16x32_bf16(A[wt][1], Bv1, C[t2][wt], 0, 0, 0);
        }
    }

    // ---- epilogue: table softmax over w (rows in-thread, quads via shfl) ----
    const int obase = (b * MM + m) * TT + tq * TBLK;
#pragma unroll
    for (int t2 = 0; t2 < 2; ++t2) {
        float se = 0.0f, sh = 0.0f;
#pragma unroll
        for (int wt = 0; wt < 4; ++wt) {
#pragma unroll
            for (int r = 0; r < 4; ++r) {
                const int w = wt * 16 + q * 4 + r;
                float h = fmaxf(fmaf(C[t2][wt][r], Amul, Cadd), 0.0f);
                float u = fminf(h, HMAX - 0.0005f) * INVH;
                int   i = (int)u;
                float fr = u - (float)i;
                unsigned p = gt[i];
                float e = (w < VMM) ? fmaf(fr, h2f_hi(p), h2f_lo(p)) : 0.0f;
                se += e;
                sh = fmaf(h, e, sh);
            }
        }
        se += __shfl_xor(se, 16, 64);
        se += __shfl_xor(se, 32, 64);
        sh += __shfl_xor(sh, 16, 64);
        sh += __shfl_xor(sh, 32, 64);
        if (q == 0)
            out[obase + (wv * 2 + t2) * 16 + nl] = sh * fast_rcp(se);
    }
}

// ---------------- fallback monolithic kernel (round-6, verified) --------
__global__ __launch_bounds__(256, 4)
void mono_kernel(const float* __restrict__ x,
                 const float* __restrict__ PA,
                 const float* __restrict__ conv_w,
                 const float* __restrict__ conv_b,
                 const float* __restrict__ bn_gamma,
                 const float* __restrict__ bn_beta,
                 const float* __restrict__ bn_mean,
                 const float* __restrict__ bn_var,
                 const float* __restrict__ w1,
                 const float* __restrict__ b1,
                 const float* __restrict__ w2,
                 const float* __restrict__ b2,
                 float* __restrict__ out)
{
    const int blk = blockIdx.x;
    const int tq  = blk & 3;
    const int m   = (blk >> 2) & 7;
    const int b   = blk >> 5;
    const int j   = threadIdx.x;

    __shared__ __align__(16) unsigned xsu[TBLK * RSTRIDE];
    __shared__ __align__(16) unsigned psu[64 * RSTRIDE];
    __shared__ __align__(16) unsigned gt[TN];

    const float scale = bn_gamma[m] * __frsqrt_rn(bn_var[m] + EPSV);
    const float Amul  = conv_w[m] * scale;
    const float Cadd  = (conv_b[m] - bn_mean[m]) * scale + bn_beta[m];

    {
        const int t  = j >> 1;
        const int hf = j & 1;
        const float* xb = x + ((b * (MM * VMM) + m * VMM) * TT + tq * TBLK + t);
        unsigned* row = &xsu[t * RSTRIDE];
        const int vp0 = hf * 13;
#pragma unroll
        for (int i = 0; i < 13; ++i) {
            int vp = vp0 + i;
            float a = 0.0f, c = 0.0f;
            if (vp < 25) { a = xb[(2 * vp) * TT]; c = xb[(2 * vp + 1) * TT]; }
            row[vp] = pack2(a, c);
        }
        if (hf) {
#pragma unroll
            for (int vp = 26; vp < 32; ++vp) row[vp] = 0u;
        }
    }
    {
        const float* pa = PA + m * (VMM * VMM);
        const int w  = j & 63;
        const int vb = (j >> 6) * 8;
#pragma unroll
        for (int i = 0; i < 8; ++i) {
            int vp = vb + i, v0 = 2 * vp, v1 = v0 + 1;
            float a = (w < VMM && v0 < VMM) ? pa[v0 * VMM + w] : 0.0f;
            float c = (w < VMM && v1 < VMM) ? pa[v1 * VMM + w] : 0.0f;
            psu[w * RSTRIDE + vp] = pack2(a, c);
        }
    }
    {
        float W1[8], B1[8], W2[8];
        float B2 = b2[m], sabs = 0.0f;
#pragma unroll
        for (int k = 0; k < 8; ++k) {
            W1[k] = w1[m * 8 + k];
            B1[k] = b1[m * 8 + k];
            W2[k] = w2[m * 8 + k];
            sabs += fabsf(W2[k]);
        }
        const float s0 = (B2 + sabs) - 8.0f;
        float gv[5];
#pragma unroll
        for (int k = 0; k < 5; ++k) {
            float h = (4 * j + k) * HSTEP;
            float s = B2 - s0;
#pragma unroll
            for (int i = 0; i < 8; ++i)
                s = fmaf(W2[i], fast_tanh(fmaf(h, W1[i], B1[i])), s);
            gv[k] = __expf(s);
        }
#pragma unroll
        for (int k = 0; k < 4; ++k)
            gt[4 * j + k] = packh2(gv[k], gv[k + 1] - gv[k]);
    }

    __syncthreads();

    const int lane = j & 63, wv = j >> 6;
    const int q = lane >> 4, nl = lane & 15;

    short8 A[4][2];
#pragma unroll
    for (int wt = 0; wt < 4; ++wt)
#pragma unroll
        for (int ks = 0; ks < 2; ++ks)
            A[wt][ks] = *(const short8*)&psu[(wt * 16 + nl) * RSTRIDE + ks * 16 + q * 4];

    float4v C[2][4];
#pragma unroll
    for (int t2 = 0; t2 < 2; ++t2)
#pragma unroll
        for (int wt = 0; wt < 4; ++wt)
            C[t2][wt] = (float4v){0.f, 0.f, 0.f, 0.f};

#pragma unroll
    for (int t2 = 0; t2 < 2; ++t2) {
        const int trow = (wv * 2 + t2) * 16 + nl;
        short8 Bv0 = *(const short8*)&xsu[trow * RSTRIDE + 0 * 16 + q * 4];
        short8 Bv1 = *(const short8*)&xsu[trow * RSTRIDE + 1 * 16 + q * 4];
#pragma unroll
        for (int wt = 0; wt < 4; ++wt) {
            C[t2][wt] = __builtin_amdgcn_mfma_f32_16x16x32_bf16(A[wt][0], Bv0, C[t2][wt], 0, 0, 0);
            C[t2][wt] = __builtin_amdgcn_mfma_f32_16x16x32_bf16(A[wt][1], Bv1, C[t2][wt], 0, 0, 0);
        }
    }

    const int obase = (b * MM + m) * TT + tq * TBLK;
#pragma unroll
    for (int t2 = 0; t2 < 2; ++t2) {
        float se = 0.0f, sh = 0.0f;
#pragma unroll
        for (int wt = 0; wt < 4; ++wt) {
#pragma unroll
            for (int r = 0; r < 4; ++r) {
                const int w = wt * 16 + q * 4 + r;
                float h = fmaxf(fmaf(C[t2][wt][r], Amul, Cadd), 0.0f);
                float u = fminf(h, HMAX - 0.0005f) * INVH;
                int   i = (int)u;
                float fr = u - (float)i;
                unsigned p = gt[i];
                float e = (w < VMM) ? fmaf(fr, h2f_hi(p), h2f_lo(p)) : 0.0f;
                se += e;
                sh = fmaf(h, e, sh);
            }
        }
        se += __shfl_xor(se, 16, 64);
        se += __shfl_xor(se, 32, 64);
        sh += __shfl_xor(sh, 16, 64);
        sh += __shfl_xor(sh, 32, 64);
        if (q == 0)
            out[obase + (wv * 2 + t2) * 16 + nl] = sh * fast_rcp(se);
    }
}

extern "C" void kernel_launch(void* const* d_in, const int* in_sizes, int n_in,
                              void* d_out, int out_size, void* d_ws, size_t ws_size,
                              hipStream_t stream) {
    const float* x        = (const float*)d_in[0];
    const float* PA       = (const float*)d_in[1];
    const float* conv_w   = (const float*)d_in[2];
    const float* conv_b   = (const float*)d_in[3];
    const float* bn_gamma = (const float*)d_in[4];
    const float* bn_beta  = (const float*)d_in[5];
    const float* bn_mean  = (const float*)d_in[6];
    const float* bn_var   = (const float*)d_in[7];
    const float* w1       = (const float*)d_in[8];
    const float* b1       = (const float*)d_in[9];
    const float* w2       = (const float*)d_in[10];
    const float* b2       = (const float*)d_in[11];
    float* out = (float*)d_out;

    if (ws_size >= (size_t)WS_NEED) {
        unsigned* ws = (unsigned*)d_ws;
        prep_kernel<<<dim3(MM), dim3(256), 0, stream>>>(PA, w1, b1, w2, b2, ws);
        intra_module_agg_kernel<<<dim3(BB * MM * (TT / TBLK)), dim3(256), 0, stream>>>(
            x, conv_w, conv_b, bn_gamma, bn_beta, bn_mean, bn_var, ws, out);
    } else {
        mono_kernel<<<dim3(BB * MM * (TT / TBLK)), dim3(256), 0, stream>>>(
            x, PA, conv_w, conv_b, bn_gamma, bn_beta, bn_mean, bn_var,
            w1, b1, w2, b2, out);
    }
}

// Round 8
// 108.092 us; speedup vs baseline: 1.3808x; 1.0412x over previous
//
#include <hip/hip_runtime.h>

// Problem constants (fixed by reference)
#define BB 64
#define TT 512
#define MM 8
#define VMM 50
#define TBLK 128         // t per block (main kernel)
#define EPSV 1e-5f

// exp(score(h)-s0) lookup table, fp16x2-packed (value, delta)
#define TN   1024
#define HMAX 16.0f
#define HSTEP (HMAX / TN)
#define INVH  (TN / HMAX)

// d_ws layout (u32 units):
//   [0, 8*TN)          : 8 per-module fp16x2 tables
//   [8*TN, +8*2048)    : 8 per-module PA^T in MFMA A-fragment order:
//                        uint4 index (wt*2+ks)*64 + lane
#define WS_GT(m)   ((m) * TN)
#define WS_PAF(m)  (MM * TN + (m) * (8 * 64 * 4))
#define WS_NEED    ((MM * TN + MM * 8 * 64 * 4) * 4)   // 98304 bytes

using short8  = __attribute__((ext_vector_type(8))) short;
using float4v = __attribute__((ext_vector_type(4))) float;

__device__ __forceinline__ float fast_rcp(float x) {
    return __builtin_amdgcn_rcpf(x);
}
__device__ __forceinline__ float fast_tanh(float x) {
    float e2 = __expf(2.0f * x);
    return fmaf(-2.0f, fast_rcp(e2 + 1.0f), 1.0f);
}
// round-to-nearest-even f32 -> bf16 pair packed into u32
__device__ __forceinline__ unsigned f2bf(float f) {
    unsigned u = __float_as_uint(f);
    return (u + 0x7FFFu + ((u >> 16) & 1u)) >> 16;
}
__device__ __forceinline__ unsigned pack2(float lo, float hi) {
    return f2bf(lo) | (f2bf(hi) << 16);
}
// f32 pair -> fp16x2 packed u32 (compiler-native _Float16, no fp16 header)
__device__ __forceinline__ unsigned packh2(float lo, float hi) {
    unsigned short a = __builtin_bit_cast(unsigned short, (_Float16)lo);
    unsigned short b = __builtin_bit_cast(unsigned short, (_Float16)hi);
    return (unsigned)a | ((unsigned)b << 16);
}
__device__ __forceinline__ float h2f_lo(unsigned p) {
    return (float)__builtin_bit_cast(_Float16, (unsigned short)(p & 0xFFFFu));
}
__device__ __forceinline__ float h2f_hi(unsigned p) {
    return (float)__builtin_bit_cast(_Float16, (unsigned short)(p >> 16));
}

// ---------------- prep kernel: 8 blocks, one per module ----------------
__global__ __launch_bounds__(256, 4)
void prep_kernel(const float* __restrict__ PA,
                 const float* __restrict__ w1,
                 const float* __restrict__ b1,
                 const float* __restrict__ w2,
                 const float* __restrict__ b2,
                 unsigned* __restrict__ ws)
{
    const int m = blockIdx.x;
    const int j = threadIdx.x;

    // ---- table: gt[i] = fp16x2(g_i, g_{i+1}-g_i), g = exp(score-s0) ----
    {
        float W1[8], B1[8], W2[8];
        float B2 = b2[m], sabs = 0.0f;
#pragma unroll
        for (int k = 0; k < 8; ++k) {
            W1[k] = w1[m * 8 + k];
            B1[k] = b1[m * 8 + k];
            W2[k] = w2[m * 8 + k];
            sabs += fabsf(W2[k]);
        }
        const float s0 = (B2 + sabs) - 8.0f;   // uniform shift; exp in fp16 range
        float gv[5];
#pragma unroll
        for (int k = 0; k < 5; ++k) {
            float h = (4 * j + k) * HSTEP;
            float s = B2 - s0;
#pragma unroll
            for (int i = 0; i < 8; ++i)
                s = fmaf(W2[i], fast_tanh(fmaf(h, W1[i], B1[i])), s);
            gv[k] = __expf(s);
        }
#pragma unroll
        for (int k = 0; k < 4; ++k)
            ws[WS_GT(m) + 4 * j + k] = packh2(gv[k], gv[k + 1] - gv[k]);
    }

    // ---- PA^T packed straight into A-fragment order ----
    // Fragment A[wt][ks] for lane: w = wt*16 + (lane&15),
    // u32 cols vp = ks*16 + (lane>>4)*4 + 0..3 (bf16 v = 2vp, 2vp+1).
    {
        const float* pa = PA + m * (VMM * VMM);
        uint4* dst = (uint4*)(ws + WS_PAF(m));
#pragma unroll
        for (int p = 0; p < 2; ++p) {
            int id   = j + p * 256;        // 0..511
            int wt   = id >> 7;
            int ks   = (id >> 6) & 1;
            int lane = id & 63;
            int w    = wt * 16 + (lane & 15);
            int vp0  = ks * 16 + (lane >> 4) * 4;
            unsigned u[4];
#pragma unroll
            for (int k = 0; k < 4; ++k) {
                int vp = vp0 + k, v0 = 2 * vp, v1 = v0 + 1;
                float a = (w < VMM && v0 < VMM) ? pa[v0 * VMM + w] : 0.0f;
                float c = (w < VMM && v1 < VMM) ? pa[v1 * VMM + w] : 0.0f;
                u[k] = pack2(a, c);
            }
            dst[(wt * 2 + ks) * 64 + lane] = make_uint4(u[0], u[1], u[2], u[3]);
        }
    }
}

// ---------------- main kernel: grid = B*M*(T/128) = 2048 ----------------
__global__ __launch_bounds__(256, 4)
void intra_module_agg_kernel(const float* __restrict__ x,
                             const float* __restrict__ conv_w,
                             const float* __restrict__ conv_b,
                             const float* __restrict__ bn_gamma,
                             const float* __restrict__ bn_beta,
                             const float* __restrict__ bn_mean,
                             const float* __restrict__ bn_var,
                             const unsigned* __restrict__ ws,
                             float* __restrict__ out)
{
    const int blk = blockIdx.x;
    const int tq  = blk & 3;          // T quarter
    const int m   = (blk >> 2) & 7;   // module
    const int b   = blk >> 5;         // batch
    const int j   = threadIdx.x;

    const int lane = j & 63, wv = j >> 6;
    const int q = lane >> 4, nl = lane & 15;

    __shared__ __align__(16) unsigned gt[TN];   // 4.1 KB only

    // ---- per-module affine constants (wave-uniform -> scalar regs) ----
    const float scale = bn_gamma[m] * __frsqrt_rn(bn_var[m] + EPSV);
    const float Amul  = conv_w[m] * scale;
    const float Cadd  = (conv_b[m] - bn_mean[m]) * scale + bn_beta[m];

    // ---- issue gt load (write to LDS later, overlapped with other loads) --
    uint4 g = ((const uint4*)(ws + WS_GT(m)))[j];

    // ---- A fragments: 8 coalesced dwordx4 loads, L2-hot ----
    const uint4* paf = (const uint4*)(ws + WS_PAF(m));
    uint4 Araw[4][2];
#pragma unroll
    for (int wt = 0; wt < 4; ++wt)
#pragma unroll
        for (int ks = 0; ks < 2; ++ks)
            Araw[wt][ks] = paf[(wt * 2 + ks) * 64 + lane];

    // ---- B fragments direct from x global ----
    // lane (nl,q) needs x[v = ks*32 + q*8 + jj][t = t0 + (wv*2+t2)*16 + nl]:
    // each load instr = 4 x 64B fully-used cache lines. OOB v clamped+zeroed.
    const int t0 = tq * TBLK;
    float xr[2][16];
#pragma unroll
    for (int t2 = 0; t2 < 2; ++t2) {
        const int t = t0 + (wv * 2 + t2) * 16 + nl;
        const float* xg = x + ((b * (MM * VMM) + m * VMM) * TT + t);
#pragma unroll
        for (int jj = 0; jj < 8; ++jj) {
            xr[t2][jj] = xg[(q * 8 + jj) * TT];            // v = 0..31, valid
        }
#pragma unroll
        for (int jj = 0; jj < 8; ++jj) {
            int v  = 32 + q * 8 + jj;                      // 32..63
            int vc = (v < VMM) ? v : 0;                    // safe address
            float tv = xg[vc * TT];
            xr[t2][8 + jj] = (v < VMM) ? tv : 0.0f;
        }
    }

    // ---- gt -> LDS (overlaps with load drain of A/B) ----
    *(uint4*)&gt[4 * j] = g;

    // ---- pack B to bf16 fragments ----
    short8 Bf[2][2];
#pragma unroll
    for (int t2 = 0; t2 < 2; ++t2) {
#pragma unroll
        for (int ks = 0; ks < 2; ++ks) {
            uint4 u;
            u.x = pack2(xr[t2][8 * ks + 0], xr[t2][8 * ks + 1]);
            u.y = pack2(xr[t2][8 * ks + 2], xr[t2][8 * ks + 3]);
            u.z = pack2(xr[t2][8 * ks + 4], xr[t2][8 * ks + 5]);
            u.w = pack2(xr[t2][8 * ks + 6], xr[t2][8 * ks + 7]);
            Bf[t2][ks] = __builtin_bit_cast(short8, u);
        }
    }

    // ---- MFMA: C[w, t] = sum_v PA[v,w] * X[t,v] ----
    float4v C[2][4];
#pragma unroll
    for (int t2 = 0; t2 < 2; ++t2)
#pragma unroll
        for (int wt = 0; wt < 4; ++wt)
            C[t2][wt] = (float4v){0.f, 0.f, 0.f, 0.f};

#pragma unroll
    for (int t2 = 0; t2 < 2; ++t2) {
#pragma unroll
        for (int wt = 0; wt < 4; ++wt) {
            C[t2][wt] = __builtin_amdgcn_mfma_f32_16x16x32_bf16(
                __builtin_bit_cast(short8, Araw[wt][0]), Bf[t2][0], C[t2][wt], 0, 0, 0);
            C[t2][wt] = __builtin_amdgcn_mfma_f32_16x16x32_bf16(
                __builtin_bit_cast(short8, Araw[wt][1]), Bf[t2][1], C[t2][wt], 0, 0, 0);
        }
    }

    __syncthreads();   // gt visible to all waves

    // ---- epilogue: table softmax over w (rows in-thread, quads via shfl) ----
    const int obase = (b * MM + m) * TT + t0;
#pragma unroll
    for (int t2 = 0; t2 < 2; ++t2) {
        float se = 0.0f, sh = 0.0f;
#pragma unroll
        for (int wt = 0; wt < 4; ++wt) {
#pragma unroll
            for (int r = 0; r < 4; ++r) {
                const int w = wt * 16 + q * 4 + r;
                float h = fmaxf(fmaf(C[t2][wt][r], Amul, Cadd), 0.0f);
                float u = fminf(h, HMAX - 0.0005f) * INVH;
                int   i = (int)u;
                float fr = u - (float)i;
                unsigned p = gt[i];
                float e = (w < VMM) ? fmaf(fr, h2f_hi(p), h2f_lo(p)) : 0.0f;
                se += e;
                sh = fmaf(h, e, sh);
            }
        }
        se += __shfl_xor(se, 16, 64);
        se += __shfl_xor(se, 32, 64);
        sh += __shfl_xor(sh, 16, 64);
        sh += __shfl_xor(sh, 32, 64);
        if (q == 0)
            out[obase + (wv * 2 + t2) * 16 + nl] = sh * fast_rcp(se);
    }
}

// ---------------- fallback monolithic kernel (round-6, verified) --------
#define RSTRIDE 36
__global__ __launch_bounds__(256, 4)
void mono_kernel(const float* __restrict__ x,
                 const float* __restrict__ PA,
                 const float* __restrict__ conv_w,
                 const float* __restrict__ conv_b,
                 const float* __restrict__ bn_gamma,
                 const float* __restrict__ bn_beta,
                 const float* __restrict__ bn_mean,
                 const float* __restrict__ bn_var,
                 const float* __restrict__ w1,
                 const float* __restrict__ b1,
                 const float* __restrict__ w2,
                 const float* __restrict__ b2,
                 float* __restrict__ out)
{
    const int blk = blockIdx.x;
    const int tq  = blk & 3;
    const int m   = (blk >> 2) & 7;
    const int b   = blk >> 5;
    const int j   = threadIdx.x;

    __shared__ __align__(16) unsigned xsu[TBLK * RSTRIDE];
    __shared__ __align__(16) unsigned psu[64 * RSTRIDE];
    __shared__ __align__(16) unsigned gt[TN];

    const float scale = bn_gamma[m] * __frsqrt_rn(bn_var[m] + EPSV);
    const float Amul  = conv_w[m] * scale;
    const float Cadd  = (conv_b[m] - bn_mean[m]) * scale + bn_beta[m];

    {
        const int t  = j >> 1;
        const int hf = j & 1;
        const float* xb = x + ((b * (MM * VMM) + m * VMM) * TT + tq * TBLK + t);
        unsigned* row = &xsu[t * RSTRIDE];
        const int vp0 = hf * 13;
#pragma unroll
        for (int i = 0; i < 13; ++i) {
            int vp = vp0 + i;
            float a = 0.0f, c = 0.0f;
            if (vp < 25) { a = xb[(2 * vp) * TT]; c = xb[(2 * vp + 1) * TT]; }
            row[vp] = pack2(a, c);
        }
        if (hf) {
#pragma unroll
            for (int vp = 26; vp < 32; ++vp) row[vp] = 0u;
        }
    }
    {
        const float* pa = PA + m * (VMM * VMM);
        const int w  = j & 63;
        const int vb = (j >> 6) * 8;
#pragma unroll
        for (int i = 0; i < 8; ++i) {
            int vp = vb + i, v0 = 2 * vp, v1 = v0 + 1;
            float a = (w < VMM && v0 < VMM) ? pa[v0 * VMM + w] : 0.0f;
            float c = (w < VMM && v1 < VMM) ? pa[v1 * VMM + w] : 0.0f;
            psu[w * RSTRIDE + vp] = pack2(a, c);
        }
    }
    {
        float W1[8], B1[8], W2[8];
        float B2 = b2[m], sabs = 0.0f;
#pragma unroll
        for (int k = 0; k < 8; ++k) {
            W1[k] = w1[m * 8 + k];
            B1[k] = b1[m * 8 + k];
            W2[k] = w2[m * 8 + k];
            sabs += fabsf(W2[k]);
        }
        const float s0 = (B2 + sabs) - 8.0f;
        float gv[5];
#pragma unroll
        for (int k = 0; k < 5; ++k) {
            float h = (4 * j + k) * HSTEP;
            float s = B2 - s0;
#pragma unroll
            for (int i = 0; i < 8; ++i)
                s = fmaf(W2[i], fast_tanh(fmaf(h, W1[i], B1[i])), s);
            gv[k] = __expf(s);
        }
#pragma unroll
        for (int k = 0; k < 4; ++k)
            gt[4 * j + k] = packh2(gv[k], gv[k + 1] - gv[k]);
    }

    __syncthreads();

    const int lane = j & 63, wv = j >> 6;
    const int q = lane >> 4, nl = lane & 15;

    short8 A[4][2];
#pragma unroll
    for (int wt = 0; wt < 4; ++wt)
#pragma unroll
        for (int ks = 0; ks < 2; ++ks)
            A[wt][ks] = *(const short8*)&psu[(wt * 16 + nl) * RSTRIDE + ks * 16 + q * 4];

    float4v C[2][4];
#pragma unroll
    for (int t2 = 0; t2 < 2; ++t2)
#pragma unroll
        for (int wt = 0; wt < 4; ++wt)
            C[t2][wt] = (float4v){0.f, 0.f, 0.f, 0.f};

#pragma unroll
    for (int t2 = 0; t2 < 2; ++t2) {
        const int trow = (wv * 2 + t2) * 16 + nl;
        short8 Bv0 = *(const short8*)&xsu[trow * RSTRIDE + 0 * 16 + q * 4];
        short8 Bv1 = *(const short8*)&xsu[trow * RSTRIDE + 1 * 16 + q * 4];
#pragma unroll
        for (int wt = 0; wt < 4; ++wt) {
            C[t2][wt] = __builtin_amdgcn_mfma_f32_16x16x32_bf16(A[wt][0], Bv0, C[t2][wt], 0, 0, 0);
            C[t2][wt] = __builtin_amdgcn_mfma_f32_16x16x32_bf16(A[wt][1], Bv1, C[t2][wt], 0, 0, 0);
        }
    }

    const int obase = (b * MM + m) * TT + tq * TBLK;
#pragma unroll
    for (int t2 = 0; t2 < 2; ++t2) {
        float se = 0.0f, sh = 0.0f;
#pragma unroll
        for (int wt = 0; wt < 4; ++wt) {
#pragma unroll
            for (int r = 0; r < 4; ++r) {
                const int w = wt * 16 + q * 4 + r;
                float h = fmaxf(fmaf(C[t2][wt][r], Amul, Cadd), 0.0f);
                float u = fminf(h, HMAX - 0.0005f) * INVH;
                int   i = (int)u;
                float fr = u - (float)i;
                unsigned p = gt[i];
                float e = (w < VMM) ? fmaf(fr, h2f_hi(p), h2f_lo(p)) : 0.0f;
                se += e;
                sh = fmaf(h, e, sh);
            }
        }
        se += __shfl_xor(se, 16, 64);
        se += __shfl_xor(se, 32, 64);
        sh += __shfl_xor(sh, 16, 64);
        sh += __shfl_xor(sh, 32, 64);
        if (q == 0)
            out[obase + (wv * 2 + t2) * 16 + nl] = sh * fast_rcp(se);
    }
}

extern "C" void kernel_launch(void* const* d_in, const int* in_sizes, int n_in,
                              void* d_out, int out_size, void* d_ws, size_t ws_size,
                              hipStream_t stream) {
    const float* x        = (const float*)d_in[0];
    const float* PA       = (const float*)d_in[1];
    const float* conv_w   = (const float*)d_in[2];
    const float* conv_b   = (const float*)d_in[3];
    const float* bn_gamma = (const float*)d_in[4];
    const float* bn_beta  = (const float*)d_in[5];
    const float* bn_mean  = (const float*)d_in[6];
    const float* bn_var   = (const float*)d_in[7];
    const float* w1       = (const float*)d_in[8];
    const float* b1       = (const float*)d_in[9];
    const float* w2       = (const float*)d_in[10];
    const float* b2       = (const float*)d_in[11];
    float* out = (float*)d_out;

    if (ws_size >= (size_t)WS_NEED) {
        unsigned* ws = (unsigned*)d_ws;
        prep_kernel<<<dim3(MM), dim3(256), 0, stream>>>(PA, w1, b1, w2, b2, ws);
        intra_module_agg_kernel<<<dim3(BB * MM * (TT / TBLK)), dim3(256), 0, stream>>>(
            x, conv_w, conv_b, bn_gamma, bn_beta, bn_mean, bn_var, ws, out);
    } else {
        mono_kernel<<<dim3(BB * MM * (TT / TBLK)), dim3(256), 0, stream>>>(
            x, PA, conv_w, conv_b, bn_gamma, bn_beta, bn_mean, bn_var,
            w1, b1, w2, b2, out);
    }
}